// Round 2
// baseline (11602.820 us; speedup 1.0000x reference)
//
#include <hip/hip_runtime.h>
#include <stdint.h>

// ---------------------------------------------------------------------------
// MyRNN on MI355X (gfx950).  BATCH=512, SEQ=256, X_DIM=512, H_DIM=1024.
//   1) cvt X, W_hh, W_xh to bf16 in ws.
//   2) v = W_hh^T @ W_hy in fp32 (folds final linear step + output dot).
//   3) Xp[b][t][j] = X@W_xh^T + bias  (one bf16 MFMA GEMM, M=131072,K=512).
//   4) Persistent recurrence kernel (256 blocks, 1/CU):
//        - 16 batch-columns x 16 j-tiles; Whh slice lives in VGPRs (K-split
//          over 4 waves, 128 VGPRs of B-frags per wave).
//        - per step: 64 MFMA/wave -> LDS cross-wave reduce -> +Xp -> sigmoid
//          -> store H slice -> column flag (device-scope) -> reload A frags.
//        - step 1 needs no sync (H1 = sigmoid(Xp_0), elementwise).
//        - last step folds out[b] = H255.v + Xp255.W_hy via atomicAdd.
// ---------------------------------------------------------------------------

typedef unsigned short u16;
typedef __attribute__((ext_vector_type(8))) __bf16 bf16x8;  // 4 VGPRs
typedef __attribute__((ext_vector_type(4))) float f32x4;

#define BATCH 512
#define SEQ 256
#define XD 512
#define HD 1024

__device__ __forceinline__ float bf2f(u16 u) {
  unsigned int x = ((unsigned int)u) << 16;
  float f;
  __builtin_memcpy(&f, &x, 4);
  return f;
}
__device__ __forceinline__ u16 f2bf(float f) {
  unsigned int x;
  __builtin_memcpy(&x, &f, 4);
  x = (x + 0x7FFFu + ((x >> 16) & 1u)) >> 16;  // RNE
  return (u16)x;
}
__device__ __forceinline__ void g2lds16(const void* g, void* l) {
  __builtin_amdgcn_global_load_lds(
      (const __attribute__((address_space(1))) unsigned int*)g,
      (__attribute__((address_space(3))) unsigned int*)l, 16, 0, 0);
}
__device__ __forceinline__ float sigmoidf(float x) {
  return 1.0f / (1.0f + __expf(-x));
}

// --------------------------- elementwise fp32 -> bf16 ----------------------
__global__ void k_cvt(const float* __restrict__ src, u16* __restrict__ dst, int n4) {
  int i = blockIdx.x * blockDim.x + threadIdx.x;
  if (i < n4) {
    float4 f = ((const float4*)src)[i];
    ushort4 u;
    u.x = f2bf(f.x); u.y = f2bf(f.y); u.z = f2bf(f.z); u.w = f2bf(f.w);
    ((ushort4*)dst)[i] = u;
  }
}

// --------------------------- v[k] = sum_j W_hy[j]*W_hh[j][k] (fp32) --------
__global__ void k_v(const float* __restrict__ whh, const float* __restrict__ why,
                    float* __restrict__ v) {
  int k = blockIdx.x * 256 + threadIdx.x;  // gridDim.x = 4
  int j0 = blockIdx.y * 128;               // gridDim.y = 8
  float s = 0.f;
  for (int j = j0; j < j0 + 128; ++j) s += why[j] * whh[j * HD + k];
  atomicAdd(&v[k], s);
}

// --------------------------- Xp GEMM ---------------------------------------
// C[r=(b*256+t)][j] = sum_k Xbf[r][k]*Wxh[j][k] + bias[j] -> Xp[r][j] (bf16).
// tile 128x128, K=512, BK=64, 4 waves each 64x64 (4x4 frags of 16x16x32).
__global__ __launch_bounds__(256) void k_xp(const u16* __restrict__ Xbf,
                                            const u16* __restrict__ Wxh,
                                            const float* __restrict__ bias,
                                            u16* __restrict__ Xp) {
  __shared__ u16 As[128 * 64];
  __shared__ u16 Bs[128 * 64];
  const int jt = blockIdx.x;   // 0..7
  const int rt = blockIdx.y;   // 0..1023
  const int tid = threadIdx.x;
  const int w = tid >> 6, l = tid & 63;
  const int mq = w & 1, nq = w >> 1;
  f32x4 acc[4][4] = {};
  const u16* Ag = Xbf + rt * 128 * XD;
  const u16* Bg = Wxh + jt * 128 * XD;
  const int srow = (l >> 3), skk = (l & 7) * 8;
  for (int kc = 0; kc < 8; ++kc) {
    const int k0 = kc * 64;
    __syncthreads();
#pragma unroll
    for (int i = 0; i < 4; ++i) {
      int idx = w * 4 + i;
      int row = idx * 8 + srow;
      g2lds16(Ag + row * XD + k0 + skk, &As[idx * 512]);
      g2lds16(Bg + row * XD + k0 + skk, &Bs[idx * 512]);
    }
    asm volatile("s_waitcnt vmcnt(0)" ::: "memory");
    __syncthreads();
#pragma unroll
    for (int ks = 0; ks < 2; ++ks) {
      bf16x8 af[4], bv[4];
      const int kk = ks * 32 + (l >> 4) * 8;
#pragma unroll
      for (int am = 0; am < 4; ++am) {
        int row = mq * 64 + am * 16 + (l & 15);
        af[am] = *(const bf16x8*)&As[row * 64 + kk];
      }
#pragma unroll
      for (int bn = 0; bn < 4; ++bn) {
        int row = nq * 64 + bn * 16 + (l & 15);
        bv[bn] = *(const bf16x8*)&Bs[row * 64 + kk];
      }
#pragma unroll
      for (int am = 0; am < 4; ++am)
#pragma unroll
        for (int bn = 0; bn < 4; ++bn)
          acc[am][bn] = __builtin_amdgcn_mfma_f32_16x16x32_bf16(af[am], bv[bn],
                                                                acc[am][bn], 0, 0, 0);
    }
  }
#pragma unroll
  for (int bn = 0; bn < 4; ++bn) {
    int jg = jt * 128 + nq * 64 + bn * 16 + (l & 15);
    float bvf = bias[jg];
#pragma unroll
    for (int am = 0; am < 4; ++am)
#pragma unroll
      for (int r = 0; r < 4; ++r) {
        int m_in = mq * 64 + am * 16 + (l >> 4) * 4 + r;
        size_t rg = (size_t)rt * 128 + m_in;   // r = b*256 + t (row-major)
        Xp[rg * HD + jg] = f2bf(acc[am][bn][r] + bvf);
      }
  }
}

// --------------------------- persistent recurrence --------------------------
__global__ __launch_bounds__(256) void k_rnn(
    const u16* __restrict__ Whh_bf, const u16* __restrict__ Xp,
    const float* __restrict__ v, const float* __restrict__ why,
    u16* __restrict__ Hb0, u16* __restrict__ Hb1,
    unsigned int* __restrict__ flags, float* __restrict__ out) {
  __shared__ float red[4][2048];  // 32 KB: per-wave partial C (32x64 f32)
  const int tid = threadIdx.x;
  const int w = tid >> 6;        // wave = k-quarter
  const int l = tid & 63;
  const int col = blockIdx.x & 15;  // batch column (32 rows); same XCD mod 8
  const int jt = blockIdx.x >> 4;   // j tile (64 cols)
  const int lm = l & 15, lq = l >> 4;

  // B frags: Whh[n = jt*64 + nb*16 + lm][k = w*256 + kb*32 + lq*8 ..+7]
  bf16x8 B[4][8];
#pragma unroll
  for (int nb = 0; nb < 4; ++nb)
#pragma unroll
    for (int kb = 0; kb < 8; ++kb)
      B[nb][kb] = *(const bf16x8*)&Whh_bf[(size_t)(jt * 64 + nb * 16 + lm) * HD +
                                          w * 256 + kb * 32 + lq * 8];

  // A_1 = sigmoid(Xp[:,t=0,:]) frags (elementwise -> no cross-block sync)
  bf16x8 A[2][8];
#pragma unroll
  for (int m = 0; m < 2; ++m)
#pragma unroll
    for (int kb = 0; kb < 8; ++kb) {
      int rb = col * 32 + m * 16 + lm;
      bf16x8 x = *(const bf16x8*)&Xp[(size_t)rb * (SEQ * HD) + w * 256 + kb * 32 + lq * 8];
      bf16x8 a;
#pragma unroll
      for (int e = 0; e < 8; ++e) a[e] = (__bf16)sigmoidf((float)x[e]);
      A[m][kb] = a;
    }

  const int orow = tid >> 3;        // 0..31: reduce-output row
  const int oc8 = (tid & 7) * 8;    // reduce-output col base within j-tile
  const int gb = col * 32 + orow;   // global batch row for this thread's outputs
  u16* Hbuf[2] = {Hb0, Hb1};

  for (int t = 1; t <= 254; ++t) {
    // prefetch Xp_t (used after reduce)
    bf16x8 xp = *(const bf16x8*)&Xp[(size_t)gb * (SEQ * HD) + (size_t)t * HD +
                                    jt * 64 + oc8];
    f32x4 acc[2][4];
#pragma unroll
    for (int m = 0; m < 2; ++m)
#pragma unroll
      for (int nb = 0; nb < 4; ++nb) acc[m][nb] = (f32x4){0.f, 0.f, 0.f, 0.f};
#pragma unroll
    for (int kb = 0; kb < 8; ++kb)
#pragma unroll
      for (int nb = 0; nb < 4; ++nb)
#pragma unroll
        for (int m = 0; m < 2; ++m)
          acc[m][nb] = __builtin_amdgcn_mfma_f32_16x16x32_bf16(A[m][kb], B[nb][kb],
                                                               acc[m][nb], 0, 0, 0);
    // cross-wave reduction via LDS
#pragma unroll
    for (int m = 0; m < 2; ++m)
#pragma unroll
      for (int nb = 0; nb < 4; ++nb)
#pragma unroll
        for (int r = 0; r < 4; ++r)
          red[w][(m * 16 + lq * 4 + r) * 64 + nb * 16 + lm] = acc[m][nb][r];
    __syncthreads();
    f32x4 a0 = *(const f32x4*)&red[0][tid * 8];
    f32x4 a1 = *(const f32x4*)&red[0][tid * 8 + 4];
#pragma unroll
    for (int w2 = 1; w2 < 4; ++w2) {
      a0 += *(const f32x4*)&red[w2][tid * 8];
      a1 += *(const f32x4*)&red[w2][tid * 8 + 4];
    }
    float pre[8] = {a0[0], a0[1], a0[2], a0[3], a1[0], a1[1], a1[2], a1[3]};
#pragma unroll
    for (int e = 0; e < 8; ++e) pre[e] += (float)xp[e];

    if (t < 254) {
      u16* Hn = Hbuf[(t + 1) & 1];
      bf16x8 hv;
#pragma unroll
      for (int e = 0; e < 8; ++e) hv[e] = (__bf16)sigmoidf(pre[e]);
      *(bf16x8*)&Hn[(size_t)gb * HD + jt * 64 + oc8] = hv;
      __threadfence();       // make this thread's H slice agent-visible
      __syncthreads();       // all threads' stores fenced before flagging
      const unsigned int fidx = (unsigned)(t + 1) * 16 + col;
      if (tid == 0) {
        __hip_atomic_fetch_add(&flags[fidx], 1u, __ATOMIC_RELEASE,
                               __HIP_MEMORY_SCOPE_AGENT);
        while (__hip_atomic_load(&flags[fidx], __ATOMIC_ACQUIRE,
                                 __HIP_MEMORY_SCOPE_AGENT) < 16u)
          __builtin_amdgcn_s_sleep(1);
      }
      __syncthreads();
      __threadfence();       // invalidate L1 before reading column's fresh H
      // A frags for next step from H_{t+1}
#pragma unroll
      for (int m = 0; m < 2; ++m)
#pragma unroll
        for (int kb = 0; kb < 8; ++kb)
          A[m][kb] = *(const bf16x8*)&Hn[(size_t)(col * 32 + m * 16 + lm) * HD +
                                         w * 256 + kb * 32 + lq * 8];
    } else {
      // epilogue: out[b] += sum_j H255[b][j]*v[j] + Xp255[b][j]*why[j]
      const float* vv = v + jt * 64 + oc8;
      const float* wy = why + jt * 64 + oc8;
      bf16x8 x255 = *(const bf16x8*)&Xp[(size_t)gb * (SEQ * HD) + (size_t)255 * HD +
                                        jt * 64 + oc8];
      float contrib = 0.f;
#pragma unroll
      for (int e = 0; e < 8; ++e) {
        contrib += sigmoidf(pre[e]) * vv[e];
        contrib += (float)x255[e] * wy[e];
      }
      contrib += __shfl_xor(contrib, 1);
      contrib += __shfl_xor(contrib, 2);
      contrib += __shfl_xor(contrib, 4);
      if ((tid & 7) == 0) atomicAdd(&out[gb], contrib);
    }
  }
}

// --------------------------- launch ----------------------------------------
extern "C" void kernel_launch(void* const* d_in, const int* in_sizes, int n_in,
                              void* d_out, int out_size, void* d_ws, size_t ws_size,
                              hipStream_t stream) {
  const float* X = (const float*)d_in[0];     // [512,256,512]
  const float* Whh = (const float*)d_in[1];   // [1024,1024]
  const float* Wxh = (const float*)d_in[2];   // [1024,512]
  const float* Why = (const float*)d_in[3];   // [1024]
  const float* bias = (const float*)d_in[4];  // [1024]
  float* out = (float*)d_out;                 // [512]

  char* ws = (char*)d_ws;
  u16* Xbf = (u16*)(ws + 0);                  // 134217728 B
  u16* Whh_bf = (u16*)(ws + 134217728);       // 2097152 B
  u16* Wxh_bf = (u16*)(ws + 136314880);       // 1048576 B
  float* v = (float*)(ws + 137363456);        // 4096 B
  u16* H0 = (u16*)(ws + 137367552);           // 1048576 B
  u16* H1 = (u16*)(ws + 138416128);           // 1048576 B
  u16* Xp = (u16*)(ws + 139464704);           // 268435456 B
  // flags alias the Xbf region (only needed after k_xp has consumed Xbf)
  unsigned int* flags = (unsigned int*)(ws + 0);  // 16384 B

  hipMemsetAsync(v, 0, 4096, stream);
  hipMemsetAsync(out, 0, (size_t)out_size * 4, stream);
  k_cvt<<<65536, 256, 0, stream>>>(X, Xbf, 16777216);
  k_cvt<<<1024, 256, 0, stream>>>(Whh, Whh_bf, 262144);
  k_cvt<<<512, 256, 0, stream>>>(Wxh, Wxh_bf, 131072);
  k_v<<<dim3(4, 8), 256, 0, stream>>>(Whh, Why, v);
  k_xp<<<dim3(8, 1024), 256, 0, stream>>>(Xbf, Wxh_bf, bias, Xp);
  hipMemsetAsync(flags, 0, 16384, stream);  // after k_xp: Xbf no longer needed
  k_rnn<<<256, 256, 0, stream>>>(Whh_bf, Xp, v, Why, H0, H1, flags, out);
}

// Round 3
// 2175.094 us; speedup vs baseline: 5.3344x; 5.3344x over previous
//
#include <hip/hip_runtime.h>
#include <stdint.h>

// ---------------------------------------------------------------------------
// MyRNN on MI355X (gfx950).  BATCH=512, SEQ=256, X_DIM=512, H_DIM=1024.
//   1) cvt X, W_hh, W_xh to bf16 in ws.
//   2) v = W_hh^T @ W_hy in fp32 (folds final linear step + output dot).
//   3) Xp[b][t][j] = X@W_xh^T + bias  (one bf16 MFMA GEMM, M=131072,K=512).
//   4) Persistent recurrence kernel (256 blocks, 1/CU):
//        - 16 batch-columns x 16 j-tiles; Whh slice in VGPRs (K-split over 4
//          waves, 128 VGPRs of B-frags per wave).
//        - per step: 64 MFMA/wave -> LDS reduce -> +Xp -> sigmoid -> H store
//          (RELAXED/AGENT atomic 8B = write-through, NO buffer_wbl2) ->
//          s_waitcnt vmcnt(0) -> flag add (RELAXED/AGENT, padded line) ->
//          poll (RELAXED/AGENT, no buffer_inv) -> A reload (RELAXED/AGENT).
//        - R2 post-mortem: __threadfence / acquire-release at agent scope
//          emit buffer_wbl2 + buffer_inv (full L2 writeback/invalidate) ->
//          43 us/step. All cache-wide ops are now eliminated.
// ---------------------------------------------------------------------------

typedef unsigned short u16;
typedef unsigned long long u64;
typedef __attribute__((ext_vector_type(8))) __bf16 bf16x8;  // 4 VGPRs
typedef __attribute__((ext_vector_type(4))) float f32x4;

#define BATCH 512
#define SEQ 256
#define XD 512
#define HD 1024

__device__ __forceinline__ float bf2f(u16 u) {
  unsigned int x = ((unsigned int)u) << 16;
  float f;
  __builtin_memcpy(&f, &x, 4);
  return f;
}
__device__ __forceinline__ u16 f2bf(float f) {
  unsigned int x;
  __builtin_memcpy(&x, &f, 4);
  x = (x + 0x7FFFu + ((x >> 16) & 1u)) >> 16;  // RNE
  return (u16)x;
}
__device__ __forceinline__ void g2lds16(const void* g, void* l) {
  __builtin_amdgcn_global_load_lds(
      (const __attribute__((address_space(1))) unsigned int*)g,
      (__attribute__((address_space(3))) unsigned int*)l, 16, 0, 0);
}
__device__ __forceinline__ float sigmoidf(float x) {
  return 1.0f / (1.0f + __expf(-x));
}
// agent-coherent 8B store/load: per-line coherence, no cache-wide ops
__device__ __forceinline__ void st8_agent(u16* p, u64 v) {
  __hip_atomic_store((u64*)p, v, __ATOMIC_RELAXED, __HIP_MEMORY_SCOPE_AGENT);
}
__device__ __forceinline__ u64 ld8_agent(const u16* p) {
  return __hip_atomic_load((const u64*)p, __ATOMIC_RELAXED, __HIP_MEMORY_SCOPE_AGENT);
}

// --------------------------- elementwise fp32 -> bf16 ----------------------
__global__ void k_cvt(const float* __restrict__ src, u16* __restrict__ dst, int n4) {
  int i = blockIdx.x * blockDim.x + threadIdx.x;
  if (i < n4) {
    float4 f = ((const float4*)src)[i];
    ushort4 u;
    u.x = f2bf(f.x); u.y = f2bf(f.y); u.z = f2bf(f.z); u.w = f2bf(f.w);
    ((ushort4*)dst)[i] = u;
  }
}

// --------------------------- v[k] = sum_j W_hy[j]*W_hh[j][k] (fp32) --------
__global__ void k_v(const float* __restrict__ whh, const float* __restrict__ why,
                    float* __restrict__ v) {
  int k = blockIdx.x * 256 + threadIdx.x;  // gridDim.x = 4
  int j0 = blockIdx.y * 128;               // gridDim.y = 8
  float s = 0.f;
  for (int j = j0; j < j0 + 128; ++j) s += why[j] * whh[j * HD + k];
  atomicAdd(&v[k], s);
}

// --------------------------- Xp GEMM ---------------------------------------
// C[r=(b*256+t)][j] = sum_k Xbf[r][k]*Wxh[j][k] + bias[j] -> Xp[r][j] (bf16).
__global__ __launch_bounds__(256) void k_xp(const u16* __restrict__ Xbf,
                                            const u16* __restrict__ Wxh,
                                            const float* __restrict__ bias,
                                            u16* __restrict__ Xp) {
  __shared__ u16 As[128 * 64];
  __shared__ u16 Bs[128 * 64];
  const int jt = blockIdx.x;   // 0..7
  const int rt = blockIdx.y;   // 0..1023
  const int tid = threadIdx.x;
  const int w = tid >> 6, l = tid & 63;
  const int mq = w & 1, nq = w >> 1;
  f32x4 acc[4][4] = {};
  const u16* Ag = Xbf + rt * 128 * XD;
  const u16* Bg = Wxh + jt * 128 * XD;
  const int srow = (l >> 3), skk = (l & 7) * 8;
  for (int kc = 0; kc < 8; ++kc) {
    const int k0 = kc * 64;
    __syncthreads();
#pragma unroll
    for (int i = 0; i < 4; ++i) {
      int idx = w * 4 + i;
      int row = idx * 8 + srow;
      g2lds16(Ag + row * XD + k0 + skk, &As[idx * 512]);
      g2lds16(Bg + row * XD + k0 + skk, &Bs[idx * 512]);
    }
    asm volatile("s_waitcnt vmcnt(0)" ::: "memory");
    __syncthreads();
#pragma unroll
    for (int ks = 0; ks < 2; ++ks) {
      bf16x8 af[4], bv[4];
      const int kk = ks * 32 + (l >> 4) * 8;
#pragma unroll
      for (int am = 0; am < 4; ++am) {
        int row = mq * 64 + am * 16 + (l & 15);
        af[am] = *(const bf16x8*)&As[row * 64 + kk];
      }
#pragma unroll
      for (int bn = 0; bn < 4; ++bn) {
        int row = nq * 64 + bn * 16 + (l & 15);
        bv[bn] = *(const bf16x8*)&Bs[row * 64 + kk];
      }
#pragma unroll
      for (int am = 0; am < 4; ++am)
#pragma unroll
        for (int bn = 0; bn < 4; ++bn)
          acc[am][bn] = __builtin_amdgcn_mfma_f32_16x16x32_bf16(af[am], bv[bn],
                                                                acc[am][bn], 0, 0, 0);
    }
  }
#pragma unroll
  for (int bn = 0; bn < 4; ++bn) {
    int jg = jt * 128 + nq * 64 + bn * 16 + (l & 15);
    float bvf = bias[jg];
#pragma unroll
    for (int am = 0; am < 4; ++am)
#pragma unroll
      for (int r = 0; r < 4; ++r) {
        int m_in = mq * 64 + am * 16 + (l >> 4) * 4 + r;
        size_t rg = (size_t)rt * 128 + m_in;   // r = b*256 + t (row-major)
        Xp[rg * HD + jg] = f2bf(acc[am][bn][r] + bvf);
      }
  }
}

// --------------------------- persistent recurrence --------------------------
#define RSTRIDE 68  // padded row stride (floats) for the reduce buffer
__global__ __launch_bounds__(256) void k_rnn(
    const u16* __restrict__ Whh_bf, const u16* __restrict__ Xp,
    const float* __restrict__ v, const float* __restrict__ why,
    u16* __restrict__ Hb0, u16* __restrict__ Hb1,
    unsigned int* __restrict__ flags, float* __restrict__ out) {
  __shared__ float red[4][32 * RSTRIDE];
  const int tid = threadIdx.x;
  const int w = tid >> 6;        // wave = k-quarter
  const int l = tid & 63;
  const int col = blockIdx.x & 15;  // batch column (32 rows)
  const int jt = blockIdx.x >> 4;   // j tile (64 cols)
  const int lm = l & 15, lq = l >> 4;

  // B frags: Whh[n = jt*64 + nb*16 + lm][k = w*256 + kb*32 + lq*8 ..+7]
  bf16x8 B[4][8];
#pragma unroll
  for (int nb = 0; nb < 4; ++nb)
#pragma unroll
    for (int kb = 0; kb < 8; ++kb)
      B[nb][kb] = *(const bf16x8*)&Whh_bf[(size_t)(jt * 64 + nb * 16 + lm) * HD +
                                          w * 256 + kb * 32 + lq * 8];

  // A_1 = sigmoid(Xp[:,t=0,:]) frags (elementwise -> no cross-block sync)
  bf16x8 A[2][8];
#pragma unroll
  for (int m = 0; m < 2; ++m)
#pragma unroll
    for (int kb = 0; kb < 8; ++kb) {
      int rb = col * 32 + m * 16 + lm;
      bf16x8 x = *(const bf16x8*)&Xp[(size_t)rb * (SEQ * HD) + w * 256 + kb * 32 + lq * 8];
      bf16x8 a;
#pragma unroll
      for (int e = 0; e < 8; ++e) a[e] = (__bf16)sigmoidf((float)x[e]);
      A[m][kb] = a;
    }

  const int orow = tid >> 3;        // 0..31: reduce-output row
  const int oc8 = (tid & 7) * 8;    // reduce-output col base within j-tile
  const int gb = col * 32 + orow;   // global batch row for this thread's outputs
  u16* Hbuf[2] = {Hb0, Hb1};

  // xp invariant: holds Xp[gb][t][jt*64+oc8 ..+7] at top of iteration t
  bf16x8 xp = *(const bf16x8*)&Xp[(size_t)gb * (SEQ * HD) + (size_t)1 * HD +
                                  jt * 64 + oc8];

  for (int t = 1; t <= 254; ++t) {
    f32x4 acc[2][4];
#pragma unroll
    for (int m = 0; m < 2; ++m)
#pragma unroll
      for (int nb = 0; nb < 4; ++nb) acc[m][nb] = (f32x4){0.f, 0.f, 0.f, 0.f};
#pragma unroll
    for (int kb = 0; kb < 8; ++kb)
#pragma unroll
      for (int nb = 0; nb < 4; ++nb)
#pragma unroll
        for (int m = 0; m < 2; ++m)
          acc[m][nb] = __builtin_amdgcn_mfma_f32_16x16x32_bf16(A[m][kb], B[nb][kb],
                                                               acc[m][nb], 0, 0, 0);
    // cross-wave reduction via LDS (row stride 68: worst conflict 2-way, free)
#pragma unroll
    for (int m = 0; m < 2; ++m)
#pragma unroll
      for (int nb = 0; nb < 4; ++nb)
#pragma unroll
        for (int r = 0; r < 4; ++r)
          red[w][(m * 16 + lq * 4 + r) * RSTRIDE + nb * 16 + lm] = acc[m][nb][r];
    __syncthreads();
    f32x4 a0 = *(const f32x4*)&red[0][orow * RSTRIDE + oc8];
    f32x4 a1 = *(const f32x4*)&red[0][orow * RSTRIDE + oc8 + 4];
#pragma unroll
    for (int w2 = 1; w2 < 4; ++w2) {
      a0 += *(const f32x4*)&red[w2][orow * RSTRIDE + oc8];
      a1 += *(const f32x4*)&red[w2][orow * RSTRIDE + oc8 + 4];
    }
    float pre[8] = {a0[0], a0[1], a0[2], a0[3], a1[0], a1[1], a1[2], a1[3]};
#pragma unroll
    for (int e = 0; e < 8; ++e) pre[e] += (float)xp[e];

    if (t < 254) {
      u16* Hn = Hbuf[(t + 1) & 1];
      union { bf16x8 v; u64 q[2]; } hv;
#pragma unroll
      for (int e = 0; e < 8; ++e) hv.v[e] = (__bf16)sigmoidf(pre[e]);
      u16* hp = &Hn[(size_t)gb * HD + jt * 64 + oc8];
      st8_agent(hp, hv.q[0]);
      st8_agent(hp + 4, hv.q[1]);
      asm volatile("s_waitcnt vmcnt(0)" ::: "memory");  // stores at coherence pt
      __syncthreads();  // whole block's H slice is agent-visible
      // prefetch next xp while the column barrier settles (normal cached load)
      xp = *(const bf16x8*)&Xp[(size_t)gb * (SEQ * HD) + (size_t)(t + 1) * HD +
                               jt * 64 + oc8];
      unsigned int* fl = &flags[(unsigned)((t + 1) * 16 + col) << 6];  // own line
      if (tid == 0) {
        __hip_atomic_fetch_add(fl, 1u, __ATOMIC_RELAXED, __HIP_MEMORY_SCOPE_AGENT);
        while (__hip_atomic_load(fl, __ATOMIC_RELAXED, __HIP_MEMORY_SCOPE_AGENT) < 16u)
          __builtin_amdgcn_s_sleep(1);
      }
      __syncthreads();
      // A frags for next step (agent-coherent loads bypass stale L1/L2)
#pragma unroll
      for (int m = 0; m < 2; ++m)
#pragma unroll
        for (int kb = 0; kb < 8; ++kb) {
          const u16* ap = &Hn[(size_t)(col * 32 + m * 16 + lm) * HD +
                              w * 256 + kb * 32 + lq * 8];
          union { bf16x8 v; u64 q[2]; } a;
          a.q[0] = ld8_agent(ap);
          a.q[1] = ld8_agent(ap + 4);
          A[m][kb] = a.v;
        }
    } else {
      // epilogue: out[b] += sum_j H255[b][j]*v[j] + Xp255[b][j]*why[j]
      const float* vv = v + jt * 64 + oc8;
      const float* wy = why + jt * 64 + oc8;
      bf16x8 x255 = *(const bf16x8*)&Xp[(size_t)gb * (SEQ * HD) + (size_t)255 * HD +
                                        jt * 64 + oc8];
      float contrib = 0.f;
#pragma unroll
      for (int e = 0; e < 8; ++e) {
        contrib += sigmoidf(pre[e]) * vv[e];
        contrib += (float)x255[e] * wy[e];
      }
      contrib += __shfl_xor(contrib, 1);
      contrib += __shfl_xor(contrib, 2);
      contrib += __shfl_xor(contrib, 4);
      if ((tid & 7) == 0) atomicAdd(&out[gb], contrib);
    }
  }
}

// --------------------------- launch ----------------------------------------
extern "C" void kernel_launch(void* const* d_in, const int* in_sizes, int n_in,
                              void* d_out, int out_size, void* d_ws, size_t ws_size,
                              hipStream_t stream) {
  const float* X = (const float*)d_in[0];     // [512,256,512]
  const float* Whh = (const float*)d_in[1];   // [1024,1024]
  const float* Wxh = (const float*)d_in[2];   // [1024,512]
  const float* Why = (const float*)d_in[3];   // [1024]
  const float* bias = (const float*)d_in[4];  // [1024]
  float* out = (float*)d_out;                 // [512]

  char* ws = (char*)d_ws;
  u16* Xbf = (u16*)(ws + 0);                  // 134217728 B
  u16* Whh_bf = (u16*)(ws + 134217728);       // 2097152 B
  u16* Wxh_bf = (u16*)(ws + 136314880);       // 1048576 B
  float* v = (float*)(ws + 137363456);        // 4096 B
  u16* H0 = (u16*)(ws + 137367552);           // 1048576 B
  u16* H1 = (u16*)(ws + 138416128);           // 1048576 B
  u16* Xp = (u16*)(ws + 139464704);           // 268435456 B
  // flags alias the Xbf region (only needed after k_xp has consumed Xbf);
  // one 256B line per (step,col): ((t*16+col)<<6) dwords, < 1 MiB total
  unsigned int* flags = (unsigned int*)(ws + 0);

  hipMemsetAsync(v, 0, 4096, stream);
  hipMemsetAsync(out, 0, (size_t)out_size * 4, stream);
  k_cvt<<<65536, 256, 0, stream>>>(X, Xbf, 16777216);
  k_cvt<<<1024, 256, 0, stream>>>(Whh, Whh_bf, 262144);
  k_cvt<<<512, 256, 0, stream>>>(Wxh, Wxh_bf, 131072);
  k_v<<<dim3(4, 8), 256, 0, stream>>>(Whh, Why, v);
  k_xp<<<dim3(8, 1024), 256, 0, stream>>>(Xbf, Wxh_bf, bias, Xp);
  hipMemsetAsync(flags, 0, 1048576, stream);  // after k_xp: Xbf region is free
  k_rnn<<<256, 256, 0, stream>>>(Whh_bf, Xp, v, Why, H0, H1, flags, out);
}